// Round 1
// baseline (742.195 us; speedup 1.0000x reference)
//
#include <hip/hip_runtime.h>
#include <math.h>

// Problem constants (from reference): S=1024, B=128, E=1024, DH=1024, OUT=1024
#define SS 1024
#define BB 128
#define EE 1024
#define DHH 1024
#define OO 1024
#define NCHUNK 8
#define ROWS_PER_CHUNK (SS / NCHUNK)          // 128
#define NWAVES 4
#define ROWS_PER_WAVE (ROWS_PER_CHUNK / NWAVES) // 32

__device__ __forceinline__ float wave_reduce_sum(float v) {
    v += __shfl_xor(v, 32);
    v += __shfl_xor(v, 16);
    v += __shfl_xor(v, 8);
    v += __shfl_xor(v, 4);
    v += __shfl_xor(v, 2);
    v += __shfl_xor(v, 1);
    return v;
}

// dst[i] = bias[i & 1023]  (both biases have length 1024)
__global__ __launch_bounds__(256) void init_bias_kernel(float* __restrict__ dst,
                                                        const float* __restrict__ bias,
                                                        int total) {
    int i = blockIdx.x * 256 + threadIdx.x;
    if (i < total) dst[i] = bias[i & 1023];
}

// C[m,n] += sum_{k in [k0,k0+Kc)} A[m,k]*B[n,k]   (NT GEMM, split-K via fp32 atomics)
// 32x32 tile, 256 threads, 2x2 micro-tile per thread.
__global__ __launch_bounds__(256) void gemm_nt_splitk(const float* __restrict__ A,
                                                      const float* __restrict__ B,
                                                      float* __restrict__ C,
                                                      int M, int N, int K, int Kc) {
    __shared__ float As[32][33];
    __shared__ float Bs[32][33];
    const int n0 = blockIdx.x * 32;
    const int m0 = blockIdx.y * 32;
    const int k0 = blockIdx.z * Kc;
    const int tid = threadIdx.x;
    const int lr = tid >> 3;          // 0..31
    const int lc = (tid & 7) << 2;    // 0,4,..,28
    const int tm = (tid >> 4) << 1;   // 0,2,..,30
    const int tn = (tid & 15) << 1;   // 0,2,..,30
    float acc00 = 0.f, acc01 = 0.f, acc10 = 0.f, acc11 = 0.f;
    for (int kk = k0; kk < k0 + Kc; kk += 32) {
        float4 av = *(const float4*)(A + (size_t)(m0 + lr) * K + kk + lc);
        float4 bv = *(const float4*)(B + (size_t)(n0 + lr) * K + kk + lc);
        As[lr][lc] = av.x; As[lr][lc + 1] = av.y; As[lr][lc + 2] = av.z; As[lr][lc + 3] = av.w;
        Bs[lr][lc] = bv.x; Bs[lr][lc + 1] = bv.y; Bs[lr][lc + 2] = bv.z; Bs[lr][lc + 3] = bv.w;
        __syncthreads();
#pragma unroll
        for (int j = 0; j < 32; ++j) {
            float a0 = As[tm][j], a1 = As[tm + 1][j];
            float b0 = Bs[tn][j], b1 = Bs[tn + 1][j];
            acc00 = fmaf(a0, b0, acc00);
            acc01 = fmaf(a0, b1, acc01);
            acc10 = fmaf(a1, b0, acc10);
            acc11 = fmaf(a1, b1, acc11);
        }
        __syncthreads();
    }
    float* c0 = C + (size_t)(m0 + tm) * N + n0 + tn;
    unsafeAtomicAdd(c0, acc00);
    unsafeAtomicAdd(c0 + 1, acc01);
    unsafeAtomicAdd(c0 + N, acc10);
    unsafeAtomicAdd(c0 + N + 1, acc11);
}

// One pass over ingr[S,B,E]: per (chunk,b) block, each wave owns full E and a
// strip of rows; online softmax with register-resident context (16 f32/lane).
// Lane e-mapping: e = k*256 + lane*4 + i  (k=0..3, i=0..3) -> all loads are
// unit-stride float4 across lanes (perfect coalescing, conflict-free LDS).
__global__ __launch_bounds__(256) void flash_attn_kernel(
        const float* __restrict__ ingr,   // [S,B,E]
        const float* __restrict__ dh,     // [B,E]
        float* __restrict__ pctx,         // [B,NCHUNK,E]  (unnormalized)
        float* __restrict__ pml)          // [B,NCHUNK,2]  (m, l)
{
    const int chunk = blockIdx.x;
    const int b = blockIdx.y;
    const int tid = threadIdx.x;
    const int wave = tid >> 6;
    const int lane = tid & 63;

    const float* dhb = dh + (size_t)b * EE + (lane << 2);
    const float4 d0 = *(const float4*)(dhb);
    const float4 d1 = *(const float4*)(dhb + 256);
    const float4 d2 = *(const float4*)(dhb + 512);
    const float4 d3 = *(const float4*)(dhb + 768);

    float m = -INFINITY, l = 0.f;
    float4 c0 = make_float4(0.f, 0.f, 0.f, 0.f);
    float4 c1 = make_float4(0.f, 0.f, 0.f, 0.f);
    float4 c2 = make_float4(0.f, 0.f, 0.f, 0.f);
    float4 c3 = make_float4(0.f, 0.f, 0.f, 0.f);

    const int s0 = chunk * ROWS_PER_CHUNK + wave * ROWS_PER_WAVE;
    const size_t row_stride = (size_t)BB * EE;
    const float* rp = ingr + ((size_t)s0 * BB + b) * EE + (lane << 2);

    float4 x0 = *(const float4*)(rp);
    float4 x1 = *(const float4*)(rp + 256);
    float4 x2 = *(const float4*)(rp + 512);
    float4 x3 = *(const float4*)(rp + 768);

    for (int j = 0; j < ROWS_PER_WAVE; ++j) {
        // prefetch next row (last iteration re-reads current row; L2-hit, cheap)
        const float* np = rp + ((j < ROWS_PER_WAVE - 1) ? row_stride : 0);
        float4 y0 = *(const float4*)(np);
        float4 y1 = *(const float4*)(np + 256);
        float4 y2 = *(const float4*)(np + 512);
        float4 y3 = *(const float4*)(np + 768);

        float p0 = x0.x * d0.x + x0.y * d0.y + x0.z * d0.z + x0.w * d0.w;
        float p1 = x1.x * d1.x + x1.y * d1.y + x1.z * d1.z + x1.w * d1.w;
        float p2 = x2.x * d2.x + x2.y * d2.y + x2.z * d2.z + x2.w * d2.w;
        float p3 = x3.x * d3.x + x3.y * d3.y + x3.z * d3.z + x3.w * d3.w;
        float p = (p0 + p1) + (p2 + p3);
        p = wave_reduce_sum(p);  // all 64 lanes now hold the full score

        float mn = fmaxf(m, p);
        float alpha = __expf(m - mn);   // m=-inf on first iter -> alpha=0
        float pe = __expf(p - mn);
        l = l * alpha + pe;
        c0.x = fmaf(pe, x0.x, c0.x * alpha);
        c0.y = fmaf(pe, x0.y, c0.y * alpha);
        c0.z = fmaf(pe, x0.z, c0.z * alpha);
        c0.w = fmaf(pe, x0.w, c0.w * alpha);
        c1.x = fmaf(pe, x1.x, c1.x * alpha);
        c1.y = fmaf(pe, x1.y, c1.y * alpha);
        c1.z = fmaf(pe, x1.z, c1.z * alpha);
        c1.w = fmaf(pe, x1.w, c1.w * alpha);
        c2.x = fmaf(pe, x2.x, c2.x * alpha);
        c2.y = fmaf(pe, x2.y, c2.y * alpha);
        c2.z = fmaf(pe, x2.z, c2.z * alpha);
        c2.w = fmaf(pe, x2.w, c2.w * alpha);
        c3.x = fmaf(pe, x3.x, c3.x * alpha);
        c3.y = fmaf(pe, x3.y, c3.y * alpha);
        c3.z = fmaf(pe, x3.z, c3.z * alpha);
        c3.w = fmaf(pe, x3.w, c3.w * alpha);
        m = mn;

        x0 = y0; x1 = y1; x2 = y2; x3 = y3;
        rp = np;
    }

    // Combine 4 wave-partials through LDS (once per block).
    __shared__ float cbuf[NWAVES][EE];   // 16 KB
    __shared__ float smm[NWAVES], sll[NWAVES];
    float4* cw = (float4*)&cbuf[wave][0];
    cw[lane] = c0;          // e = lane*4
    cw[64 + lane] = c1;     // e = 256 + lane*4
    cw[128 + lane] = c2;    // e = 512 + lane*4
    cw[192 + lane] = c3;    // e = 768 + lane*4
    if (lane == 0) { smm[wave] = m; sll[wave] = l; }
    __syncthreads();

    const float M = fmaxf(fmaxf(smm[0], smm[1]), fmaxf(smm[2], smm[3]));
    const float w0 = __expf(smm[0] - M);
    const float w1 = __expf(smm[1] - M);
    const float w2 = __expf(smm[2] - M);
    const float w3 = __expf(smm[3] - M);
    const float L = sll[0] * w0 + sll[1] * w1 + sll[2] * w2 + sll[3] * w3;

    float4 a0 = ((const float4*)&cbuf[0][0])[tid];
    float4 a1 = ((const float4*)&cbuf[1][0])[tid];
    float4 a2 = ((const float4*)&cbuf[2][0])[tid];
    float4 a3 = ((const float4*)&cbuf[3][0])[tid];
    float4 r;
    r.x = a0.x * w0 + a1.x * w1 + a2.x * w2 + a3.x * w3;
    r.y = a0.y * w0 + a1.y * w1 + a2.y * w2 + a3.y * w3;
    r.z = a0.z * w0 + a1.z * w1 + a2.z * w2 + a3.z * w3;
    r.w = a0.w * w0 + a1.w * w1 + a2.w * w2 + a3.w * w3;

    float4* dst = (float4*)(pctx + ((size_t)b * NCHUNK + chunk) * EE);
    dst[tid] = r;
    if (tid == 0) {
        pml[((size_t)b * NCHUNK + chunk) * 2] = M;
        pml[((size_t)b * NCHUNK + chunk) * 2 + 1] = L;
    }
}

// Merge the NCHUNK partials per b, normalize, and build concat[b,0:2048].
__global__ __launch_bounds__(256) void combine_kernel(
        const float* __restrict__ pctx,  // [B,NCHUNK,E]
        const float* __restrict__ pml,   // [B,NCHUNK,2]
        const float* __restrict__ dec,   // [B,DH]
        float* __restrict__ concat)      // [B, E+DH]
{
    const int b = blockIdx.x;
    const int tid = threadIdx.x;
    float M = -INFINITY;
#pragma unroll
    for (int c = 0; c < NCHUNK; ++c)
        M = fmaxf(M, pml[((size_t)b * NCHUNK + c) * 2]);
    float w[NCHUNK];
    float L = 0.f;
#pragma unroll
    for (int c = 0; c < NCHUNK; ++c) {
        w[c] = __expf(pml[((size_t)b * NCHUNK + c) * 2] - M);
        L += pml[((size_t)b * NCHUNK + c) * 2 + 1] * w[c];
    }
    const float invL = 1.f / L;
    float4 r = make_float4(0.f, 0.f, 0.f, 0.f);
#pragma unroll
    for (int c = 0; c < NCHUNK; ++c) {
        float4 v = ((const float4*)(pctx + ((size_t)b * NCHUNK + c) * EE))[tid];
        r.x = fmaf(v.x, w[c], r.x);
        r.y = fmaf(v.y, w[c], r.y);
        r.z = fmaf(v.z, w[c], r.z);
        r.w = fmaf(v.w, w[c], r.w);
    }
    r.x *= invL; r.y *= invL; r.z *= invL; r.w *= invL;
    float* crow = concat + (size_t)b * (EE + DHH);
    ((float4*)crow)[tid] = r;
    // ref part of concat
    float4 dv = ((const float4*)(dec + (size_t)b * DHH))[tid];
    ((float4*)(crow + EE))[tid] = dv;
}

extern "C" void kernel_launch(void* const* d_in, const int* in_sizes, int n_in,
                              void* d_out, int out_size, void* d_ws, size_t ws_size,
                              hipStream_t stream) {
    const float* ingr = (const float*)d_in[0];  // [S,B,E]
    const float* dec  = (const float*)d_in[1];  // [1,B,DH]
    const float* Wp   = (const float*)d_in[2];  // [E,DH]
    const float* bp   = (const float*)d_in[3];  // [E]
    const float* Wo   = (const float*)d_in[4];  // [OUT,E+DH]
    const float* bo   = (const float*)d_in[5];  // [OUT]
    float* out = (float*)d_out;                 // [1,B,OUT]

    // workspace layout (fp32): dh | pctx | pml | concat  (~5.3 MB total)
    float* dhbuf  = (float*)d_ws;                          // B*E
    float* pctx   = dhbuf + (size_t)BB * EE;               // B*NCHUNK*E
    float* pml    = pctx + (size_t)BB * NCHUNK * EE;       // B*NCHUNK*2
    float* concat = pml + (size_t)BB * NCHUNK * 2;         // B*(E+DH)

    // 1) dh = dec @ W_proj^T + b_proj
    init_bias_kernel<<<(BB * EE) / 256, 256, 0, stream>>>(dhbuf, bp, BB * EE);
    gemm_nt_splitk<<<dim3(EE / 32, BB / 32, 4), 256, 0, stream>>>(
        dec, Wp, dhbuf, BB, EE, DHH, DHH / 4);

    // 2) single-pass flash attention over ingr
    flash_attn_kernel<<<dim3(NCHUNK, BB), 256, 0, stream>>>(ingr, dhbuf, pctx, pml);

    // 3) merge partials, build concat = [context, dec]
    combine_kernel<<<BB, 256, 0, stream>>>(pctx, pml, dec, concat);

    // 4) out = concat @ W_out^T + b_out
    init_bias_kernel<<<(BB * OO) / 256, 256, 0, stream>>>(out, bo, BB * OO);
    gemm_nt_splitk<<<dim3(OO / 32, BB / 32, 4), 256, 0, stream>>>(
        concat, Wo, out, BB, OO, EE + DHH, (EE + DHH) / 4);
}